// Round 15
// baseline (858.161 us; speedup 1.0000x reference)
//
#include <hip/hip_runtime.h>
#include <math.h>

// Problem constants
#define B_  8
#define LQ_ 2048
#define LK_ 2048
#define H_  1024

#define TAU      4e-3f
#define FIX_CAP  32768
#define FIX_E    8
#define SCL      256.0f
#define SCLQ     16.0f
#define INV_SS   (1.0f / 1048576.0f)  // 2^-20

// BLAS sgemm K-blocking (VERIFIED R9): kc=512 -> blocks {512,512}
#define KBLK 512

typedef unsigned short ushort_t;
typedef __attribute__((ext_vector_type(8))) _Float16 v8h;
typedef __attribute__((ext_vector_type(8))) short  v8s;
typedef __attribute__((ext_vector_type(4))) float  v4f;
typedef __attribute__((ext_vector_type(4))) float  f4;
typedef __attribute__((ext_vector_type(4))) int    i4;
typedef __attribute__((ext_vector_type(4))) short  s4;

#if defined(__has_builtin)
#if __has_builtin(__builtin_amdgcn_global_load_lds)
#define HAS_GLDS 1
#endif
#endif

// ---- helpers -------------------------------------------------------------
__device__ __forceinline__ ushort_t f2bf(float x) {
  unsigned u = __float_as_uint(x);
  u = (u + 0x7FFFu + ((u >> 16) & 1u)) >> 16;  // RNE
  return (ushort_t)u;
}
__device__ __forceinline__ void split2h(float x, ushort_t& h, ushort_t& l) {
  union { _Float16 f; ushort_t u; } a, b;
  a.f = (_Float16)x;
  b.f = (_Float16)(x - (float)a.f);
  h = a.u; l = b.u;
}

__device__ __forceinline__ void gld_lds16(void* lds_dst, const void* g_src) {
#ifdef HAS_GLDS
  __builtin_amdgcn_global_load_lds((const __attribute__((address_space(1))) void*)g_src,
                                   (__attribute__((address_space(3))) void*)lds_dst,
                                   16, 0, 0);
#else
  *(i4*)lds_dst = *(const i4*)g_src;
#endif
}

// XCD-chunked bijective block remap (T1, VERIFIED R11: FETCH 337->167MB).
__device__ __forceinline__ void xcd_remap(int& bx, int& by, int& bz) {
  const int nx = gridDim.x, ny = gridDim.y;
  const int nwg = nx * ny * gridDim.z;
  const int hwid = bx + nx * (by + ny * bz);
  const int work = (hwid & 7) * (nwg >> 3) + (hwid >> 3);
  bx = work % nx;
  const int t = work / nx;
  by = t % ny;
  bz = t / ny;
}

#define WAIT_VM0() asm volatile("s_waitcnt vmcnt(0)" ::: "memory")
#define WAIT_VM(n) asm volatile("s_waitcnt vmcnt(" #n ")" ::: "memory")
#define LGKM0_FENCE() do { asm volatile("s_waitcnt lgkmcnt(0)" ::: "memory"); \
                           __builtin_amdgcn_sched_barrier(0); } while (0)

__global__ void k_zero(int* p) { *p = 0; }

// ---- K0a: elementwise f16 hi/lo split ------------------------------------
__global__ void k_split(const float* __restrict__ x, ushort_t* __restrict__ hi,
                        ushort_t* __restrict__ lo, int n4, float scale) {
  int stride = gridDim.x * blockDim.x;
  for (int i = blockIdx.x * blockDim.x + threadIdx.x; i < n4; i += stride) {
    f4 v = ((const f4*)x)[i];
    s4 h, l;
#pragma unroll
    for (int j = 0; j < 4; j++) {
      ushort_t hb, lb; split2h(v[j] * scale, hb, lb);
      h[j] = (short)hb; l[j] = (short)lb;
    }
    ((s4*)hi)[i] = h;
    ((s4*)lo)[i] = l;
  }
}

// ---- K0b: tiled transpose (+optional f16 split) --------------------------
template <int SPLIT>
__global__ void k_transpose(const float* __restrict__ X, ushort_t* __restrict__ Yhi,
                            ushort_t* __restrict__ Ylo, int R, int C, float scale) {
  __shared__ float t[32][33];
  const int b = blockIdx.z;
  const float* Xb = X + (size_t)b * R * C;
  ushort_t* Yh = Yhi + (size_t)b * R * C;
  const int c0 = blockIdx.x * 32, r0 = blockIdx.y * 32;
  const int tx = threadIdx.x, ty = threadIdx.y;  // (32,8)
#pragma unroll
  for (int i = 0; i < 4; i++)
    t[ty + 8 * i][tx] = Xb[(size_t)(r0 + ty + 8 * i) * C + c0 + tx];
  __syncthreads();
#pragma unroll
  for (int i = 0; i < 4; i++) {
    float v = t[tx][ty + 8 * i] * scale;
    size_t o = (size_t)(c0 + ty + 8 * i) * R + r0 + tx;
    if (SPLIT) {
      ushort_t h, l; split2h(v, h, l);
      Yh[o] = h;
      (Ylo + (size_t)b * R * C)[o] = l;
    } else {
      Yh[o] = f2bf(v);
    }
  }
}

// LDS chunk swizzle (VERIFIED R10, conflicts -> 0): chunk c of row r at slot
// c ^ ((r>>1)&3); pre-swizzled GLOBAL source, linear LDS dest, XOR on read.

// ---- phase-split f16x2 GEMM: BM=256, BN=256, BK=32, 8 waves, 2-stage -----
// m201-style schedule: tile-top {vmcnt(0); barrier}; B-frags cached in regs;
// 4 phases of {4 A ds_reads | 4 stage glds (phases 0-1) ; barrier; lgkm(0);
// setprio(1); 24 MFMA; setprio(0); barrier}.  Numerics identical to R14.
// EPI 0: write f16 hi/lo split.  EPI 1: S, sigmoid G, hat, flag.
template <int EPI>
__global__ __launch_bounds__(512, 1)
void gemm_hx2p(const ushort_t* __restrict__ Ahi, const ushort_t* __restrict__ Alo,
               const ushort_t* __restrict__ Bhi, const ushort_t* __restrict__ Blo,
               int KD, long strideAB, long strideBB, int N,
               ushort_t* __restrict__ OutHi, ushort_t* __restrict__ OutLo, long strideOB,
               float* __restrict__ S, float* __restrict__ G, ushort_t* __restrict__ Hatb,
               const int* __restrict__ mask, int* __restrict__ cnt, int* __restrict__ flist) {
  int bx = blockIdx.x, by = blockIdx.y, bz = blockIdx.z;
  xcd_remap(bx, by, bz);
  const int b  = bz;
  const int m0 = by * 256;
  const int n0 = bx * 256;
  const ushort_t* Ah = Ahi + (size_t)b * strideAB + (size_t)m0 * KD;
  const ushort_t* Al = Alo + (size_t)b * strideAB + (size_t)m0 * KD;
  const ushort_t* Bh = Bhi + (size_t)b * strideBB + (size_t)n0 * KD;
  const ushort_t* Bl = Blo + (size_t)b * strideBB + (size_t)n0 * KD;

  // 2 stages x [A-hi 16K | A-lo 16K | B-hi 16K | B-lo 16K] = 128KB
  __shared__ __attribute__((aligned(16))) char lds[2 * 65536];

  const int tid  = threadIdx.x;        // 0..511
  const int lane = tid & 63;
  const int w    = tid >> 6;           // 0..7
  const int wm   = (w >> 2) * 128;     // wave row base (0/128)
  const int wn   = (w & 3) * 64;       // wave col base (0..192)
  const int fr   = lane & 15;
  const int cq   = lane >> 4;

  v4f acc[8][4] = {};

  const int r4 = tid >> 2;
  const int gc = (tid & 3) ^ ((r4 >> 1) & 3);
  const size_t go1 = (size_t)r4 * KD + gc * 8;
  const size_t go2 = (size_t)(r4 + 128) * KD + gc * 8;
  const int lo16 = tid * 16;

#define STG_A(t_) do {                                                  \
    char* sb_ = lds + ((t_) & 1) * 65536;                               \
    const int kk_ = (t_) * 32;                                          \
    gld_lds16(sb_ + lo16,          Ah + go1 + kk_);                     \
    gld_lds16(sb_ + 8192  + lo16,  Ah + go2 + kk_);                     \
    gld_lds16(sb_ + 16384 + lo16,  Al + go1 + kk_);                     \
    gld_lds16(sb_ + 24576 + lo16,  Al + go2 + kk_);                     \
  } while (0)
#define STG_B(t_) do {                                                  \
    char* sb_ = lds + ((t_) & 1) * 65536;                               \
    const int kk_ = (t_) * 32;                                          \
    gld_lds16(sb_ + 32768 + lo16,  Bh + go1 + kk_);                     \
    gld_lds16(sb_ + 40960 + lo16,  Bh + go2 + kk_);                     \
    gld_lds16(sb_ + 49152 + lo16,  Bl + go1 + kk_);                     \
    gld_lds16(sb_ + 57344 + lo16,  Bl + go2 + kk_);                     \
  } while (0)

  const int nT = KD / 32;
  STG_A(0); STG_B(0);
  for (int t = 0; t < nT; ++t) {
    WAIT_VM0();                     // own stage(t) loads complete
    __builtin_amdgcn_s_barrier();   // stage(t) published by all waves

    const char* sb = lds + (t & 1) * 65536;
    // B fragments for the whole tile (held in regs across phases)
    v8h b_h[4], b_l[4];
#pragma unroll
    for (int j = 0; j < 4; j++) {
      const int Rb = wn + j * 16 + fr;
      const int ob = Rb * 64 + ((cq ^ ((Rb >> 1) & 3)) << 4);
      b_h[j] = *(const v8h*)(sb + 32768 + ob);
      b_l[j] = *(const v8h*)(sb + 49152 + ob);
    }

#pragma unroll
    for (int p = 0; p < 4; p++) {
      // phase p: A fragments for rows 2p, 2p+1
      v8h a_h0, a_l0, a_h1, a_l1;
      {
        const int Ra0 = wm + (2 * p) * 16 + fr;
        const int oa0 = Ra0 * 64 + ((cq ^ ((Ra0 >> 1) & 3)) << 4);
        a_h0 = *(const v8h*)(sb + oa0);
        a_l0 = *(const v8h*)(sb + 16384 + oa0);
        const int Ra1 = wm + (2 * p + 1) * 16 + fr;
        const int oa1 = Ra1 * 64 + ((cq ^ ((Ra1 >> 1) & 3)) << 4);
        a_h1 = *(const v8h*)(sb + oa1);
        a_l1 = *(const v8h*)(sb + 16384 + oa1);
      }
      if (p == 0 && t + 1 < nT) STG_A(t + 1);
      if (p == 1 && t + 1 < nT) STG_B(t + 1);

      __builtin_amdgcn_s_barrier();
      LGKM0_FENCE();
      __builtin_amdgcn_s_setprio(1);
#pragma unroll
      for (int j = 0; j < 4; j++) {
        acc[2 * p][j]     = __builtin_amdgcn_mfma_f32_16x16x32_f16(a_h0, b_h[j], acc[2 * p][j], 0, 0, 0);
        acc[2 * p][j]     = __builtin_amdgcn_mfma_f32_16x16x32_f16(a_h0, b_l[j], acc[2 * p][j], 0, 0, 0);
        acc[2 * p][j]     = __builtin_amdgcn_mfma_f32_16x16x32_f16(a_l0, b_h[j], acc[2 * p][j], 0, 0, 0);
        acc[2 * p + 1][j] = __builtin_amdgcn_mfma_f32_16x16x32_f16(a_h1, b_h[j], acc[2 * p + 1][j], 0, 0, 0);
        acc[2 * p + 1][j] = __builtin_amdgcn_mfma_f32_16x16x32_f16(a_h1, b_l[j], acc[2 * p + 1][j], 0, 0, 0);
        acc[2 * p + 1][j] = __builtin_amdgcn_mfma_f32_16x16x32_f16(a_l1, b_h[j], acc[2 * p + 1][j], 0, 0, 0);
      }
      __builtin_amdgcn_s_setprio(0);
      __builtin_amdgcn_s_barrier();
    }
  }
#undef STG_A
#undef STG_B

  // epilogue: C/D layout col = lane&15, row = (lane>>4)*4 + reg
  const int rg = (lane >> 4) * 4;
#pragma unroll
  for (int i = 0; i < 8; i++)
#pragma unroll
    for (int j = 0; j < 4; j++)
#pragma unroll
      for (int r = 0; r < 4; r++) {
        const int grow = m0 + wm + i * 16 + rg + r;
        const int gcol = n0 + wn + j * 16 + fr;
        const float v = acc[i][j][r];
        if (EPI == 0) {
          size_t o = (size_t)b * strideOB + (size_t)grow * N + gcol;
          ushort_t h, l; split2h(v, h, l);
          OutHi[o] = h; OutLo[o] = l;
        } else {
          size_t o = ((size_t)b * LQ_ + grow) * N + gcol;
          const float sv = v * INV_SS;
          S[o] = sv;
          int mk = mask[b * N + gcol];
          const float g = mk ? 1.0f / (1.0f + expf(-sv)) : 0.0f;
          G[o] = g;
          Hatb[o] = (g > 0.5f) ? (ushort_t)0x3F80 : (ushort_t)0;
          if (mk && fabsf(sv) < TAU) {
            int idx = atomicAdd(cnt, 1);
            if (idx < FIX_CAP) flist[idx] = (b << 22) | (grow << 11) | gcol;
          }
        }
      }
}

// ---- BLAS-sgemm emulation fixup (kc=512, VERIFIED) -----------------------
__global__ __launch_bounds__(256)
void k_fix_blas(const int* __restrict__ cnt, const int* __restrict__ flist,
                const float* __restrict__ Q, const float* __restrict__ Kx,
                const float* __restrict__ W, float* __restrict__ S,
                float* __restrict__ G, ushort_t* __restrict__ Hatb) {
  const int n = min(*cnt, FIX_CAP);
  const int base = blockIdx.x * FIX_E;
  if (base >= n) return;
  const int ne = min(FIX_E, n - base);
  const int tid = threadIdx.x;

  __shared__ float qs[FIX_E][H_];
  __shared__ float aA[FIX_E][H_];
  __shared__ int   ent[FIX_E];

  if (tid < FIX_E) ent[tid] = flist[base + ((tid < ne) ? tid : 0)];
  __syncthreads();

  for (int e = 0; e < FIX_E; e++) {
    const int en = ent[e];
    const int b = en >> 22, q = (en >> 11) & 2047;
    const float* Qr = Q + ((size_t)b * LQ_ + q) * H_;
    for (int i = tid; i < H_; i += 256) qs[e][i] = Qr[i];
  }
  __syncthreads();

  float atot[FIX_E][4];
  float acc[FIX_E][4];
  const float* Wp = W + tid * 4;
#pragma unroll
  for (int blk = 0; blk < 2; blk++) {
    const int h0 = blk * KBLK;
    const int h1 = h0 + KBLK;
#pragma unroll
    for (int e = 0; e < FIX_E; e++)
#pragma unroll
      for (int j = 0; j < 4; j++) acc[e][j] = 0.f;
    for (int h = h0; h < h1; h++) {
      f4 w = *(const f4*)(Wp + (size_t)h * H_);
#pragma unroll
      for (int e = 0; e < FIX_E; e++) {
        const float qv = qs[e][h];
        acc[e][0] = fmaf(qv, w[0], acc[e][0]);
        acc[e][1] = fmaf(qv, w[1], acc[e][1]);
        acc[e][2] = fmaf(qv, w[2], acc[e][2]);
        acc[e][3] = fmaf(qv, w[3], acc[e][3]);
      }
    }
#pragma unroll
    for (int e = 0; e < FIX_E; e++)
#pragma unroll
      for (int j = 0; j < 4; j++)
        atot[e][j] = (blk == 0) ? acc[e][j] : __fadd_rn(atot[e][j], acc[e][j]);
  }
#pragma unroll
  for (int e = 0; e < FIX_E; e++) {
    aA[e][tid * 4 + 0] = atot[e][0];
    aA[e][tid * 4 + 1] = atot[e][1];
    aA[e][tid * 4 + 2] = atot[e][2];
    aA[e][tid * 4 + 3] = atot[e][3];
  }
  __syncthreads();

  if (tid < ne) {
    const int e = tid;
    const int en = ent[e];
    const int b = en >> 22, q = (en >> 11) & 2047, k = en & 2047;
    const float* Kr = Kx + ((size_t)b * LK_ + k) * H_;
    const float* Ar = aA[e];
    float stot = 0.f;
#pragma unroll
    for (int blk = 0; blk < 2; blk++) {
      const int d0 = blk * KBLK;
      const int d1 = d0 + KBLK;
      float a = 0.f;
#pragma unroll 16
      for (int d = d0; d < d1; d++) a = fmaf(Ar[d], Kr[d], a);
      stot = (blk == 0) ? a : __fadd_rn(stot, a);
    }
    size_t o = ((size_t)b * LQ_ + q) * LK_ + k;
    S[o] = stot;
    const float g = 1.0f / (1.0f + expf(-stot));
    G[o] = g;
    Hatb[o] = (g > 0.5f) ? (ushort_t)0x3F80 : (ushort_t)0;
  }
}

// ---- K3: in-place masked row softmax; emits bf16 P -----------------------
__global__ void k_softmax(float* __restrict__ S, const int* __restrict__ mask,
                          ushort_t* __restrict__ Pb) {
  const int row = blockIdx.x;
  const int b   = row >> 11;
  float* Sr = S + (size_t)row * LK_;
  const int* mr = mask + b * LK_;
  const int tid = threadIdx.x;
  const int c0 = tid * 8;

  float v[8]; int mk[8];
  f4 v0 = *(const f4*)&Sr[c0];
  f4 v1 = *(const f4*)&Sr[c0 + 4];
  i4 m0 = *(const i4*)&mr[c0];
  i4 m1 = *(const i4*)&mr[c0 + 4];
#pragma unroll
  for (int j = 0; j < 4; j++) { v[j] = v0[j]; v[4 + j] = v1[j]; mk[j] = m0[j]; mk[4 + j] = m1[j]; }

  float mx = -INFINITY;
#pragma unroll
  for (int j = 0; j < 8; j++) if (mk[j]) mx = fmaxf(mx, v[j]);
#pragma unroll
  for (int off = 32; off; off >>= 1) mx = fmaxf(mx, __shfl_xor(mx, off));
  __shared__ float redm[4], reds[4];
  const int lane = tid & 63, wid = tid >> 6;
  if (lane == 0) redm[wid] = mx;
  __syncthreads();
  mx = fmaxf(fmaxf(redm[0], redm[1]), fmaxf(redm[2], redm[3]));

  float e[8], sum = 0.f;
#pragma unroll
  for (int j = 0; j < 8; j++) { e[j] = mk[j] ? expf(v[j] - mx) : 0.f; sum += e[j]; }
#pragma unroll
  for (int off = 32; off; off >>= 1) sum += __shfl_xor(sum, off);
  if (lane == 0) reds[wid] = sum;
  __syncthreads();
  sum = reds[0] + reds[1] + reds[2] + reds[3];
  const float inv = 1.0f / sum;

  f4 o0, o1;
  v8s pb;
#pragma unroll
  for (int j = 0; j < 4; j++) {
    o0[j] = e[j] * inv; o1[j] = e[4 + j] * inv;
    pb[j] = (short)f2bf(o0[j]); pb[4 + j] = (short)f2bf(o1[j]);
  }
  *(f4*)&Sr[c0] = o0;
  *(f4*)&Sr[c0 + 4] = o1;
  *(v8s*)&Pb[(size_t)row * LK_ + c0] = pb;
}

// ---- pipelined fused dual PV: BM=128, BN=256, BK=32, 8 waves, 3-stage ----
//   O0 = Pb . Vt^T,  O1 = hatb . Vt^T  (B staged once, shared)
__global__ __launch_bounds__(512, 1)
void gemm_pv2p(const ushort_t* __restrict__ P, const ushort_t* __restrict__ Hb,
               const ushort_t* __restrict__ Bt,
               float* __restrict__ O0, float* __restrict__ O1) {
  int bx = blockIdx.x, by = blockIdx.y, bz = blockIdx.z;
  xcd_remap(bx, by, bz);
  const int b  = bz;
  const int m0 = by * 128;
  const int n0 = bx * 256;
  const ushort_t* Pa = P  + ((size_t)b * LQ_ + m0) * (size_t)LK_;
  const ushort_t* Ha = Hb + ((size_t)b * LQ_ + m0) * (size_t)LK_;
  const ushort_t* Bb = Bt + ((size_t)b * H_  + n0) * (size_t)LK_;

  __shared__ __attribute__((aligned(16))) char lds[3 * 32768];

  const int tid  = threadIdx.x;
  const int lane = tid & 63;
  const int w    = tid >> 6;
  const int wm   = (w >> 2) * 64;
  const int wn   = (w & 3) * 64;
  const int fr   = lane & 15;
  const int cq   = lane >> 4;

  v4f acc0[4][4] = {}, acc1[4][4] = {};

  const int r4 = tid >> 2;
  const int gc = (tid & 3) ^ ((r4 >> 1) & 3);
  const size_t goA  = (size_t)r4 * LK_ + gc * 8;
  const size_t goB1 = (size_t)(r4 + 128) * LK_ + gc * 8;
  const int lo16 = tid * 16;

#define STG_PV(t_) do {                                                  \
    char* sb = lds + ((t_) % 3) * 32768;                                 \
    const int kk = (t_) * 32;                                            \
    gld_lds16(sb + lo16,          Pa + goA  + kk);                       \
    gld_lds16(sb + 8192 + lo16,   Ha + goA  + kk);                       \
    gld_lds16(sb + 16384 + lo16,  Bb + goA  + kk);                       \
    gld_lds16(sb + 24576 + lo16,  Bb + goB1 + kk);                       \
  } while (0)

  const int nT = LK_ / 32;   // 64
  STG_PV(0);
  STG_PV(1);
  for (int t = 0; t < nT; ++t) {
    if (t + 1 < nT) WAIT_VM(4);
    else            WAIT_VM(0);
    __builtin_amdgcn_s_barrier();

    const char* sb = lds + (t % 3) * 32768;
    v8s pf[4], hf[4], bf[4];
#pragma unroll
    for (int i = 0; i < 4; i++) {
      const int Ra = wm + i * 16 + fr;
      const int oa = Ra * 64 + ((cq ^ ((Ra >> 1) & 3)) << 4);
      pf[i] = *(const v8s*)(sb + oa);
      hf[i] = *(const v8s*)(sb + 8192 + oa);
      const int Rb = wn + i * 16 + fr;
      bf[i] = *(const v8s*)(sb + 16384 + Rb * 64 + ((cq ^ ((Rb >> 1) & 3)) << 4));
    }
    if (t + 2 < nT) STG_PV(t + 2);

    __builtin_amdgcn_s_setprio(1);
#pragma unroll
    for (int i = 0; i < 4; i++)
#pragma unroll
      for (int j = 0; j < 4; j++) {
        acc0[i][j] = __builtin_amdgcn_mfma_f32_16x16x32_bf16(pf[i], bf[j], acc0[i][j], 0, 0, 0);
        acc1[i][j] = __builtin_amdgcn_mfma_f32_16x16x32_bf16(hf[i], bf[j], acc1[i][j], 0, 0, 0);
      }
    __builtin_amdgcn_s_setprio(0);
  }
#undef STG_PV

  const int rg = (lane >> 4) * 4;
#pragma unroll
  for (int i = 0; i < 4; i++)
#pragma unroll
    for (int j = 0; j < 4; j++)
#pragma unroll
      for (int r = 0; r < 4; r++) {
        const int grow = m0 + wm + i * 16 + rg + r;
        const int gcol = n0 + wn + j * 16 + fr;
        const size_t o = ((size_t)b * LQ_ + grow) * H_ + gcol;
        O0[o] = acc0[i][j][r];
        O1[o] = acc1[i][j][r];
      }
}

// ---- launch --------------------------------------------------------------
extern "C" void kernel_launch(void* const* d_in, const int* in_sizes, int n_in,
                              void* d_out, int out_size, void* d_ws, size_t ws_size,
                              hipStream_t stream) {
  const float* Q = (const float*)d_in[0];
  const float* K = (const float*)d_in[1];
  const float* V = (const float*)d_in[2];
  const float* W = (const float*)d_in[3];
  const int* mask = (const int*)d_in[4];

  float* out0 = (float*)d_out;
  float* out1 = out0 + (size_t)B_ * LQ_ * H_;
  float* out2 = out1 + (size_t)B_ * LQ_ * H_;
  float* out3 = out2 + (size_t)B_ * LQ_ * LK_;

  const size_t NQ = (size_t)B_ * LQ_ * H_;
  char* ws = (char*)d_ws;
  int* cnt   = (int*)ws;                    ws += 256;
  int* flist = (int*)ws;                    ws += FIX_CAP * 4;
  ushort_t* Qhi = (ushort_t*)ws;            ws += NQ * 2;
  ushort_t* Qlo = (ushort_t*)ws;            ws += NQ * 2;
  ushort_t* Khi = (ushort_t*)ws;            ws += NQ * 2;
  ushort_t* Klo = (ushort_t*)ws;            ws += NQ * 2;
  ushort_t* Ahi = (ushort_t*)ws;            ws += NQ * 2;
  ushort_t* Alo = (ushort_t*)ws;            ws += NQ * 2;
  ushort_t* Vt  = (ushort_t*)ws;            ws += NQ * 2;
  ushort_t* Wthi = (ushort_t*)ws;           ws += (size_t)H_ * H_ * 2;
  ushort_t* Wtlo = (ushort_t*)ws;

  ushort_t* hatb = Qhi;   // dead after K1
  ushort_t* Pb   = Ahi;   // dead after K2

  k_zero<<<1, 1, 0, stream>>>(cnt);

  k_split<<<2048, 256, 0, stream>>>(Q, Qhi, Qlo, (int)(NQ / 4), SCLQ);
  k_split<<<2048, 256, 0, stream>>>(K, Khi, Klo, (int)(NQ / 4), SCL);
  dim3 tb(32, 8);
  k_transpose<1><<<dim3(32, 32, 1), tb, 0, stream>>>(W, Wthi, Wtlo, H_, H_, SCL);
  k_transpose<0><<<dim3(32, 64, B_), tb, 0, stream>>>(V, Vt, nullptr, LK_, H_, 1.0f);

  // K1: A' = (16Q) @ (256 W)  (f16x2 3-pass, phase-split)
  gemm_hx2p<0><<<dim3(H_ / 256, LQ_ / 256, B_), 512, 0, stream>>>(
      Qhi, Qlo, Wthi, Wtlo, H_, (long)LQ_ * H_, 0L, H_,
      Ahi, Alo, (long)LQ_ * H_, nullptr, nullptr, nullptr, nullptr, nullptr, nullptr);

  // K2: s' = A' @ (256 K)^T  -> S, G, hat, flags
  gemm_hx2p<1><<<dim3(LK_ / 256, LQ_ / 256, B_), 512, 0, stream>>>(
      Ahi, Alo, Khi, Klo, H_, (long)LQ_ * H_, (long)LK_ * H_, LK_,
      nullptr, nullptr, 0L, out2, out3, hatb, mask, cnt, flist);

  // K2.5: BLAS {512,512}-blocked f32 emulation fixup
  k_fix_blas<<<FIX_CAP / FIX_E, 256, 0, stream>>>(cnt, flist, Q, K, W, out2, out3, hatb);

  // K3: masked softmax; emits bf16 P
  k_softmax<<<B_ * LQ_, 256, 0, stream>>>(out2, mask, Pb);

  // K4+K5 fused: dual PV -> out0, out1
  gemm_pv2p<<<dim3(H_ / 256, LQ_ / 128, B_), 512, 0, stream>>>(Pb, hatb, Vt, out0, out1);
}

// Round 16
// 854.030 us; speedup vs baseline: 1.0048x; 1.0048x over previous
//
#include <hip/hip_runtime.h>
#include <math.h>

// Problem constants
#define B_  8
#define LQ_ 2048
#define LK_ 2048
#define H_  1024

#define TAU      4e-3f
#define FIX_CAP  32768
#define FIX_E    8
#define SCL      256.0f
#define SCLQ     16.0f
#define INV_SS   (1.0f / 1048576.0f)  // 2^-20

// BLAS sgemm K-blocking (VERIFIED R9): kc=512 -> blocks {512,512}
#define KBLK 512

typedef unsigned short ushort_t;
typedef __attribute__((ext_vector_type(8))) _Float16 v8h;
typedef __attribute__((ext_vector_type(8))) short  v8s;
typedef __attribute__((ext_vector_type(4))) float  v4f;
typedef __attribute__((ext_vector_type(4))) float  f4;
typedef __attribute__((ext_vector_type(4))) int    i4;
typedef __attribute__((ext_vector_type(4))) short  s4;

#if defined(__has_builtin)
#if __has_builtin(__builtin_amdgcn_global_load_lds)
#define HAS_GLDS 1
#endif
#endif

// ---- helpers -------------------------------------------------------------
__device__ __forceinline__ ushort_t f2bf(float x) {
  unsigned u = __float_as_uint(x);
  u = (u + 0x7FFFu + ((u >> 16) & 1u)) >> 16;  // RNE
  return (ushort_t)u;
}
__device__ __forceinline__ void split2h(float x, ushort_t& h, ushort_t& l) {
  union { _Float16 f; ushort_t u; } a, b;
  a.f = (_Float16)x;
  b.f = (_Float16)(x - (float)a.f);
  h = a.u; l = b.u;
}

__device__ __forceinline__ void gld_lds16(void* lds_dst, const void* g_src) {
#ifdef HAS_GLDS
  __builtin_amdgcn_global_load_lds((const __attribute__((address_space(1))) void*)g_src,
                                   (__attribute__((address_space(3))) void*)lds_dst,
                                   16, 0, 0);
#else
  *(i4*)lds_dst = *(const i4*)g_src;
#endif
}

// XCD-chunked bijective block remap (T1, VERIFIED R11: FETCH 337->167MB).
__device__ __forceinline__ void xcd_remap(int& bx, int& by, int& bz) {
  const int nx = gridDim.x, ny = gridDim.y;
  const int nwg = nx * ny * gridDim.z;
  const int hwid = bx + nx * (by + ny * bz);
  const int work = (hwid & 7) * (nwg >> 3) + (hwid >> 3);
  bx = work % nx;
  const int t = work / nx;
  by = t % ny;
  bz = t / ny;
}

#define WAIT_VM(n) asm volatile("s_waitcnt vmcnt(" #n ")" ::: "memory")

// ---- K0 fused prologue: Q-split | K-split | W-transpose+split | V-transpose
// grid: [0,2048) Qsplit, [2048,4096) Ksplit, [4096,5120) Wt, [5120,21504) Vt.
__global__ __launch_bounds__(256)
void k_prep(const float* __restrict__ Q, const float* __restrict__ K,
            const float* __restrict__ W, const float* __restrict__ V,
            ushort_t* __restrict__ Qhi, ushort_t* __restrict__ Qlo,
            ushort_t* __restrict__ Khi, ushort_t* __restrict__ Klo,
            ushort_t* __restrict__ Wthi, ushort_t* __restrict__ Wtlo,
            ushort_t* __restrict__ Vt, int* __restrict__ cnt) {
  const int blk = blockIdx.x;
  const int tid = threadIdx.x;
  if (blk == 0 && tid == 0) *cnt = 0;

  if (blk < 4096) {
    // splits: 2048 blocks each, stride loop over n4 = NQ/4
    const int sb = blk & 2047;
    const float* x = (blk < 2048) ? Q : K;
    ushort_t* hi = (blk < 2048) ? Qhi : Khi;
    ushort_t* lo = (blk < 2048) ? Qlo : Klo;
    const float scale = (blk < 2048) ? SCLQ : SCL;
    const int n4 = (int)((size_t)B_ * LQ_ * H_ / 4);
    for (int i = sb * 256 + tid; i < n4; i += 2048 * 256) {
      f4 v = ((const f4*)x)[i];
      s4 h, l;
#pragma unroll
      for (int j = 0; j < 4; j++) {
        ushort_t hb, lb; split2h(v[j] * scale, hb, lb);
        h[j] = (short)hb; l[j] = (short)lb;
      }
      ((s4*)hi)[i] = h;
      ((s4*)lo)[i] = l;
    }
    return;
  }

  // transposes
  __shared__ float t[32][33];
  const int tx = tid & 31, ty = tid >> 5;  // (32,8)
  int bx, by, bz, R, C, SPLIT;
  const float* X;
  float scale;
  if (blk < 5120) {  // W: [1024][1024], split
    const int wb = blk - 4096;
    bx = wb & 31; by = wb >> 5; bz = 0; R = H_; C = H_; SPLIT = 1; X = W; scale = SCL;
  } else {           // V: [2048][1024] per batch, no split
    const int vb = blk - 5120;
    bx = vb & 31; by = (vb >> 5) & 63; bz = vb >> 11; R = LK_; C = H_; SPLIT = 0; X = V; scale = 1.0f;
  }
  const float* Xb = X + (size_t)bz * R * C;
  const int c0 = bx * 32, r0 = by * 32;
#pragma unroll
  for (int i = 0; i < 4; i++)
    t[ty + 8 * i][tx] = Xb[(size_t)(r0 + ty + 8 * i) * C + c0 + tx];
  __syncthreads();
#pragma unroll
  for (int i = 0; i < 4; i++) {
    float v = t[tx][ty + 8 * i] * scale;
    size_t o = (size_t)(c0 + ty + 8 * i) * R + r0 + tx;
    if (SPLIT) {
      ushort_t h, l; split2h(v, h, l);
      Wthi[o] = h; Wtlo[o] = l;
    } else {
      (Vt + (size_t)bz * R * C)[o] = f2bf(v);
    }
  }
}

// LDS chunk swizzle (VERIFIED R10, conflicts -> 0): chunk c of row r at slot
// c ^ ((r>>1)&3); pre-swizzled GLOBAL source, linear LDS dest, XOR on read.

// ---- f16x2 GEMM: BM=256, BN=256, BK=32, 8 waves, 2-stage (R14 loop) ------
// Wave-tile 128x64.  Epilogues: 2-byte outputs staged through LDS for
// coalesced 256B/thread drains (kills partial-sector write amplification).
// EPI 0: write f16 hi/lo split.  EPI 1: S, sigmoid G, hat, flag.
template <int EPI>
__global__ __launch_bounds__(512, 1)
void gemm_hx2p(const ushort_t* __restrict__ Ahi, const ushort_t* __restrict__ Alo,
               const ushort_t* __restrict__ Bhi, const ushort_t* __restrict__ Blo,
               int KD, long strideAB, long strideBB, int N,
               ushort_t* __restrict__ OutHi, ushort_t* __restrict__ OutLo, long strideOB,
               float* __restrict__ S, float* __restrict__ G, ushort_t* __restrict__ Hatb,
               const int* __restrict__ mask, int* __restrict__ cnt, int* __restrict__ flist) {
  int bx = blockIdx.x, by = blockIdx.y, bz = blockIdx.z;
  xcd_remap(bx, by, bz);
  const int b  = bz;
  const int m0 = by * 256;
  const int n0 = bx * 256;
  const ushort_t* Ah = Ahi + (size_t)b * strideAB + (size_t)m0 * KD;
  const ushort_t* Al = Alo + (size_t)b * strideAB + (size_t)m0 * KD;
  const ushort_t* Bh = Bhi + (size_t)b * strideBB + (size_t)n0 * KD;
  const ushort_t* Bl = Blo + (size_t)b * strideBB + (size_t)n0 * KD;

  // 2 stages x [A-hi 16K | A-lo 16K | B-hi 16K | B-lo 16K] = 128KB
  __shared__ __attribute__((aligned(16))) char lds[2 * 65536];

  const int tid  = threadIdx.x;        // 0..511
  const int lane = tid & 63;
  const int w    = tid >> 6;           // 0..7
  const int wm   = (w >> 2) * 128;     // wave row base (0/128)
  const int wn   = (w & 3) * 64;       // wave col base (0..192)
  const int fr   = lane & 15;
  const int cq   = lane >> 4;

  v4f acc[8][4] = {};

  const int r4 = tid >> 2;
  const int gc = (tid & 3) ^ ((r4 >> 1) & 3);
  const size_t go1 = (size_t)r4 * KD + gc * 8;
  const size_t go2 = (size_t)(r4 + 128) * KD + gc * 8;
  const int lo16 = tid * 16;

#define STG_HX(t_) do {                                                  \
    char* sb_ = lds + ((t_) & 1) * 65536;                                \
    const int kk_ = (t_) * 32;                                           \
    gld_lds16(sb_ + lo16,          Ah + go1 + kk_);                      \
    gld_lds16(sb_ + 8192  + lo16,  Ah + go2 + kk_);                      \
    gld_lds16(sb_ + 16384 + lo16,  Al + go1 + kk_);                      \
    gld_lds16(sb_ + 24576 + lo16,  Al + go2 + kk_);                      \
    gld_lds16(sb_ + 32768 + lo16,  Bh + go1 + kk_);                      \
    gld_lds16(sb_ + 40960 + lo16,  Bh + go2 + kk_);                      \
    gld_lds16(sb_ + 49152 + lo16,  Bl + go1 + kk_);                      \
    gld_lds16(sb_ + 57344 + lo16,  Bl + go2 + kk_);                      \
  } while (0)

  const int nT = KD / 32;
  STG_HX(0);
  for (int t = 0; t < nT; ++t) {
    WAIT_VM(0);                     // own stage(t) complete
    __builtin_amdgcn_s_barrier();   // stage(t) published; buf (t+1)&1 free
    if (t + 1 < nT) STG_HX(t + 1);  // overlaps MFMA below

    const char* sb = lds + (t & 1) * 65536;
    v8h b_h[4], b_l[4];
#pragma unroll
    for (int j = 0; j < 4; j++) {
      const int Rb = wn + j * 16 + fr;
      const int ob = Rb * 64 + ((cq ^ ((Rb >> 1) & 3)) << 4);
      b_h[j] = *(const v8h*)(sb + 32768 + ob);
      b_l[j] = *(const v8h*)(sb + 49152 + ob);
    }
    __builtin_amdgcn_s_setprio(1);
#pragma unroll
    for (int i = 0; i < 8; i++) {
      const int Ra = wm + i * 16 + fr;
      const int oa = Ra * 64 + ((cq ^ ((Ra >> 1) & 3)) << 4);
      v8h a_h = *(const v8h*)(sb + oa);
      v8h a_l = *(const v8h*)(sb + 16384 + oa);
#pragma unroll
      for (int j = 0; j < 4; j++) {
        acc[i][j] = __builtin_amdgcn_mfma_f32_16x16x32_f16(a_h, b_h[j], acc[i][j], 0, 0, 0);
        acc[i][j] = __builtin_amdgcn_mfma_f32_16x16x32_f16(a_h, b_l[j], acc[i][j], 0, 0, 0);
        acc[i][j] = __builtin_amdgcn_mfma_f32_16x16x32_f16(a_l, b_h[j], acc[i][j], 0, 0, 0);
      }
    }
    __builtin_amdgcn_s_setprio(0);
  }
#undef STG_HX

  // ---- epilogue.  C/D layout: col = lane&15, row = (lane>>4)*4 + reg ----
  const int rg = (lane >> 4) * 4;
  ushort_t* Ls = (ushort_t*)lds;   // 256x256 shorts = 128KB (staging done)

  if (EPI == 1) {
    // direct S/G writes (256B-contiguous per wave-row: no amplification);
    // hat staged in LDS, drained coalesced.
    __syncthreads();
#pragma unroll
    for (int i = 0; i < 8; i++)
#pragma unroll
      for (int j = 0; j < 4; j++)
#pragma unroll
        for (int r = 0; r < 4; r++) {
          const int tr = wm + i * 16 + rg + r;    // tile row
          const int tc = wn + j * 16 + fr;        // tile col
          const int grow = m0 + tr;
          const int gcol = n0 + tc;
          const float sv = acc[i][j][r] * INV_SS;
          size_t o = ((size_t)b * LQ_ + grow) * N + gcol;
          S[o] = sv;
          int mk = mask[b * N + gcol];
          const float g = mk ? 1.0f / (1.0f + expf(-sv)) : 0.0f;
          G[o] = g;
          Ls[tr * 256 + tc] = (g > 0.5f) ? (ushort_t)0x3F80 : (ushort_t)0;
          if (mk && fabsf(sv) < TAU) {
            int idx = atomicAdd(cnt, 1);
            if (idx < FIX_CAP) flist[idx] = (b << 22) | (grow << 11) | gcol;
          }
        }
    __syncthreads();
    // drain hat: thread -> one row-half (128 shorts = 256B contiguous)
    const int hr = tid >> 1, hc = (tid & 1) * 128;
    ushort_t* hdst = Hatb + ((size_t)b * LQ_ + m0 + hr) * N + n0 + hc;
    const ushort_t* hsrc = &Ls[hr * 256 + hc];
#pragma unroll
    for (int u = 0; u < 16; u++) ((v8s*)hdst)[u] = ((const v8s*)hsrc)[u];
  } else {
    // EPI 0: two passes (hi then lo) staged through LDS, coalesced drains.
#pragma unroll
    for (int pass = 0; pass < 2; pass++) {
      __syncthreads();
#pragma unroll
      for (int i = 0; i < 8; i++)
#pragma unroll
        for (int j = 0; j < 4; j++)
#pragma unroll
          for (int r = 0; r < 4; r++) {
            const int tr = wm + i * 16 + rg + r;
            const int tc = wn + j * 16 + fr;
            ushort_t h, l; split2h(acc[i][j][r], h, l);
            Ls[tr * 256 + tc] = pass ? l : h;
          }
      __syncthreads();
      ushort_t* dst0 = pass ? OutLo : OutHi;
      const int hr = tid >> 1, hc = (tid & 1) * 128;
      ushort_t* dst = dst0 + (size_t)b * strideOB + (size_t)(m0 + hr) * N + n0 + hc;
      const ushort_t* src = &Ls[hr * 256 + hc];
#pragma unroll
      for (int u = 0; u < 16; u++) ((v8s*)dst)[u] = ((const v8s*)src)[u];
    }
  }
}

// ---- BLAS-sgemm emulation fixup (kc=512, VERIFIED) -----------------------
__global__ __launch_bounds__(256)
void k_fix_blas(const int* __restrict__ cnt, const int* __restrict__ flist,
                const float* __restrict__ Q, const float* __restrict__ Kx,
                const float* __restrict__ W, float* __restrict__ S,
                float* __restrict__ G, ushort_t* __restrict__ Hatb) {
  const int n = min(*cnt, FIX_CAP);
  const int base = blockIdx.x * FIX_E;
  if (base >= n) return;
  const int ne = min(FIX_E, n - base);
  const int tid = threadIdx.x;

  __shared__ float qs[FIX_E][H_];
  __shared__ float aA[FIX_E][H_];
  __shared__ int   ent[FIX_E];

  if (tid < FIX_E) ent[tid] = flist[base + ((tid < ne) ? tid : 0)];
  __syncthreads();

  for (int e = 0; e < FIX_E; e++) {
    const int en = ent[e];
    const int b = en >> 22, q = (en >> 11) & 2047;
    const float* Qr = Q + ((size_t)b * LQ_ + q) * H_;
    for (int i = tid; i < H_; i += 256) qs[e][i] = Qr[i];
  }
  __syncthreads();

  float atot[FIX_E][4];
  float acc[FIX_E][4];
  const float* Wp = W + tid * 4;
#pragma unroll
  for (int blk = 0; blk < 2; blk++) {
    const int h0 = blk * KBLK;
    const int h1 = h0 + KBLK;
#pragma unroll
    for (int e = 0; e < FIX_E; e++)
#pragma unroll
      for (int j = 0; j < 4; j++) acc[e][j] = 0.f;
    for (int h = h0; h < h1; h++) {
      f4 w = *(const f4*)(Wp + (size_t)h * H_);
#pragma unroll
      for (int e = 0; e < FIX_E; e++) {
        const float qv = qs[e][h];
        acc[e][0] = fmaf(qv, w[0], acc[e][0]);
        acc[e][1] = fmaf(qv, w[1], acc[e][1]);
        acc[e][2] = fmaf(qv, w[2], acc[e][2]);
        acc[e][3] = fmaf(qv, w[3], acc[e][3]);
      }
    }
#pragma unroll
    for (int e = 0; e < FIX_E; e++)
#pragma unroll
      for (int j = 0; j < 4; j++)
        atot[e][j] = (blk == 0) ? acc[e][j] : __fadd_rn(atot[e][j], acc[e][j]);
  }
#pragma unroll
  for (int e = 0; e < FIX_E; e++) {
    aA[e][tid * 4 + 0] = atot[e][0];
    aA[e][tid * 4 + 1] = atot[e][1];
    aA[e][tid * 4 + 2] = atot[e][2];
    aA[e][tid * 4 + 3] = atot[e][3];
  }
  __syncthreads();

  if (tid < ne) {
    const int e = tid;
    const int en = ent[e];
    const int b = en >> 22, q = (en >> 11) & 2047, k = en & 2047;
    const float* Kr = Kx + ((size_t)b * LK_ + k) * H_;
    const float* Ar = aA[e];
    float stot = 0.f;
#pragma unroll
    for (int blk = 0; blk < 2; blk++) {
      const int d0 = blk * KBLK;
      const int d1 = d0 + KBLK;
      float a = 0.f;
#pragma unroll 16
      for (int d = d0; d < d1; d++) a = fmaf(Ar[d], Kr[d], a);
      stot = (blk == 0) ? a : __fadd_rn(stot, a);
    }
    size_t o = ((size_t)b * LQ_ + q) * LK_ + k;
    S[o] = stot;
    const float g = 1.0f / (1.0f + expf(-stot));
    G[o] = g;
    Hatb[o] = (g > 0.5f) ? (ushort_t)0x3F80 : (ushort_t)0;
  }
}

// ---- K3: in-place masked row softmax; emits bf16 P -----------------------
__global__ void k_softmax(float* __restrict__ S, const int* __restrict__ mask,
                          ushort_t* __restrict__ Pb) {
  const int row = blockIdx.x;
  const int b   = row >> 11;
  float* Sr = S + (size_t)row * LK_;
  const int* mr = mask + b * LK_;
  const int tid = threadIdx.x;
  const int c0 = tid * 8;

  float v[8]; int mk[8];
  f4 v0 = *(const f4*)&Sr[c0];
  f4 v1 = *(const f4*)&Sr[c0 + 4];
  i4 m0 = *(const i4*)&mr[c0];
  i4 m1 = *(const i4*)&mr[c0 + 4];
#pragma unroll
  for (int j = 0; j < 4; j++) { v[j] = v0[j]; v[4 + j] = v1[j]; mk[j] = m0[j]; mk[4 + j] = m1[j]; }

  float mx = -INFINITY;
#pragma unroll
  for (int j = 0; j < 8; j++) if (mk[j]) mx = fmaxf(mx, v[j]);
#pragma unroll
  for (int off = 32; off; off >>= 1) mx = fmaxf(mx, __shfl_xor(mx, off));
  __shared__ float redm[4], reds[4];
  const int lane = tid & 63, wid = tid >> 6;
  if (lane == 0) redm[wid] = mx;
  __syncthreads();
  mx = fmaxf(fmaxf(redm[0], redm[1]), fmaxf(redm[2], redm[3]));

  float e[8], sum = 0.f;
#pragma unroll
  for (int j = 0; j < 8; j++) { e[j] = mk[j] ? expf(v[j] - mx) : 0.f; sum += e[j]; }
#pragma unroll
  for (int off = 32; off; off >>= 1) sum += __shfl_xor(sum, off);
  if (lane == 0) reds[wid] = sum;
  __syncthreads();
  sum = reds[0] + reds[1] + reds[2] + reds[3];
  const float inv = 1.0f / sum;

  f4 o0, o1;
  v8s pb;
#pragma unroll
  for (int j = 0; j < 4; j++) {
    o0[j] = e[j] * inv; o1[j] = e[4 + j] * inv;
    pb[j] = (short)f2bf(o0[j]); pb[4 + j] = (short)f2bf(o1[j]);
  }
  *(f4*)&Sr[c0] = o0;
  *(f4*)&Sr[c0 + 4] = o1;
  *(v8s*)&Pb[(size_t)row * LK_ + c0] = pb;
}

// ---- pipelined fused dual PV: BM=128, BN=256, BK=32, 8 waves, 3-stage ----
//   O0 = Pb . Vt^T,  O1 = hatb . Vt^T  (B staged once, shared)
__global__ __launch_bounds__(512, 1)
void gemm_pv2p(const ushort_t* __restrict__ P, const ushort_t* __restrict__ Hb,
               const ushort_t* __restrict__ Bt,
               float* __restrict__ O0, float* __restrict__ O1) {
  int bx = blockIdx.x, by = blockIdx.y, bz = blockIdx.z;
  xcd_remap(bx, by, bz);
  const int b  = bz;
  const int m0 = by * 128;
  const int n0 = bx * 256;
  const ushort_t* Pa = P  + ((size_t)b * LQ_ + m0) * (size_t)LK_;
  const ushort_t* Ha = Hb + ((size_t)b * LQ_ + m0) * (size_t)LK_;
  const ushort_t* Bb = Bt + ((size_t)b * H_  + n0) * (size_t)LK_;

  __shared__ __attribute__((aligned(16))) char lds[3 * 32768];

  const int tid  = threadIdx.x;
  const int lane = tid & 63;
  const int w    = tid >> 6;
  const int wm   = (w >> 2) * 64;
  const int wn   = (w & 3) * 64;
  const int fr   = lane & 15;
  const int cq   = lane >> 4;

  v4f acc0[4][4] = {}, acc1[4][4] = {};

  const int r4 = tid >> 2;
  const int gc = (tid & 3) ^ ((r4 >> 1) & 3);
  const size_t goA  = (size_t)r4 * LK_ + gc * 8;
  const size_t goB1 = (size_t)(r4 + 128) * LK_ + gc * 8;
  const int lo16 = tid * 16;

#define STG_PV(t_) do {                                                  \
    char* sb = lds + ((t_) % 3) * 32768;                                 \
    const int kk = (t_) * 32;                                            \
    gld_lds16(sb + lo16,          Pa + goA  + kk);                       \
    gld_lds16(sb + 8192 + lo16,   Ha + goA  + kk);                       \
    gld_lds16(sb + 16384 + lo16,  Bb + goA  + kk);                       \
    gld_lds16(sb + 24576 + lo16,  Bb + goB1 + kk);                       \
  } while (0)

  const int nT = LK_ / 32;   // 64
  STG_PV(0);
  STG_PV(1);
  for (int t = 0; t < nT; ++t) {
    if (t + 1 < nT) WAIT_VM(4);
    else            WAIT_VM(0);
    __builtin_amdgcn_s_barrier();

    const char* sb = lds + (t % 3) * 32768;
    v8s pf[4], hf[4], bf[4];
#pragma unroll
    for (int i = 0; i < 4; i++) {
      const int Ra = wm + i * 16 + fr;
      const int oa = Ra * 64 + ((cq ^ ((Ra >> 1) & 3)) << 4);
      pf[i] = *(const v8s*)(sb + oa);
      hf[i] = *(const v8s*)(sb + 8192 + oa);
      const int Rb = wn + i * 16 + fr;
      bf[i] = *(const v8s*)(sb + 16384 + Rb * 64 + ((cq ^ ((Rb >> 1) & 3)) << 4));
    }
    if (t + 2 < nT) STG_PV(t + 2);

    __builtin_amdgcn_s_setprio(1);
#pragma unroll
    for (int i = 0; i < 4; i++)
#pragma unroll
      for (int j = 0; j < 4; j++) {
        acc0[i][j] = __builtin_amdgcn_mfma_f32_16x16x32_bf16(pf[i], bf[j], acc0[i][j], 0, 0, 0);
        acc1[i][j] = __builtin_amdgcn_mfma_f32_16x16x32_bf16(hf[i], bf[j], acc1[i][j], 0, 0, 0);
      }
    __builtin_amdgcn_s_setprio(0);
  }
#undef STG_PV

  const int rg = (lane >> 4) * 4;
#pragma unroll
  for (int i = 0; i < 4; i++)
#pragma unroll
    for (int j = 0; j < 4; j++)
#pragma unroll
      for (int r = 0; r < 4; r++) {
        const int grow = m0 + wm + i * 16 + rg + r;
        const int gcol = n0 + wn + j * 16 + fr;
        const size_t o = ((size_t)b * LQ_ + grow) * H_ + gcol;
        O0[o] = acc0[i][j][r];
        O1[o] = acc1[i][j][r];
      }
}

// ---- launch --------------------------------------------------------------
extern "C" void kernel_launch(void* const* d_in, const int* in_sizes, int n_in,
                              void* d_out, int out_size, void* d_ws, size_t ws_size,
                              hipStream_t stream) {
  const float* Q = (const float*)d_in[0];
  const float* K = (const float*)d_in[1];
  const float* V = (const float*)d_in[2];
  const float* W = (const float*)d_in[3];
  const int* mask = (const int*)d_in[4];

  float* out0 = (float*)d_out;
  float* out1 = out0 + (size_t)B_ * LQ_ * H_;
  float* out2 = out1 + (size_t)B_ * LQ_ * H_;
  float* out3 = out2 + (size_t)B_ * LQ_ * LK_;

  const size_t NQ = (size_t)B_ * LQ_ * H_;
  char* ws = (char*)d_ws;
  int* cnt   = (int*)ws;                    ws += 256;
  int* flist = (int*)ws;                    ws += FIX_CAP * 4;
  ushort_t* Qhi = (ushort_t*)ws;            ws += NQ * 2;
  ushort_t* Qlo = (ushort_t*)ws;            ws += NQ * 2;
  ushort_t* Khi = (ushort_t*)ws;            ws += NQ * 2;
  ushort_t* Klo = (ushort_t*)ws;            ws += NQ * 2;
  ushort_t* Ahi = (ushort_t*)ws;            ws += NQ * 2;
  ushort_t* Alo = (ushort_t*)ws;            ws += NQ * 2;
  ushort_t* Vt  = (ushort_t*)ws;            ws += NQ * 2;
  ushort_t* Wthi = (ushort_t*)ws;           ws += (size_t)H_ * H_ * 2;
  ushort_t* Wtlo = (ushort_t*)ws;

  ushort_t* hatb = Qhi;   // dead after K1
  ushort_t* Pb   = Ahi;   // dead after K2

  // K0: fused prologue (splits + transposes + cnt zero)
  k_prep<<<21504, 256, 0, stream>>>(Q, K, W, V, Qhi, Qlo, Khi, Klo,
                                    Wthi, Wtlo, Vt, cnt);

  // K1: A' = (16Q) @ (256 W)  (f16x2 3-pass)
  gemm_hx2p<0><<<dim3(H_ / 256, LQ_ / 256, B_), 512, 0, stream>>>(
      Qhi, Qlo, Wthi, Wtlo, H_, (long)LQ_ * H_, 0L, H_,
      Ahi, Alo, (long)LQ_ * H_, nullptr, nullptr, nullptr, nullptr, nullptr, nullptr);

  // K2: s' = A' @ (256 K)^T  -> S, G, hat, flags
  gemm_hx2p<1><<<dim3(LK_ / 256, LQ_ / 256, B_), 512, 0, stream>>>(
      Ahi, Alo, Khi, Klo, H_, (long)LQ_ * H_, (long)LK_ * H_, LK_,
      nullptr, nullptr, 0L, out2, out3, hatb, mask, cnt, flist);

  // K2.5: BLAS {512,512}-blocked f32 emulation fixup
  k_fix_blas<<<FIX_CAP / FIX_E, 256, 0, stream>>>(cnt, flist, Q, K, W, out2, out3, hatb);

  // K3: masked softmax; emits bf16 P
  k_softmax<<<B_ * LQ_, 256, 0, stream>>>(out2, mask, Pb);

  // K4+K5 fused: dual PV -> out0, out1
  gemm_pv2p<<<dim3(H_ / 256, LQ_ / 128, B_), 512, 0, stream>>>(Pb, hatb, Vt, out0, out1);
}

// Round 17
// 832.279 us; speedup vs baseline: 1.0311x; 1.0261x over previous
//
#include <hip/hip_runtime.h>
#include <math.h>

// Problem constants
#define B_  8
#define LQ_ 2048
#define LK_ 2048
#define H_  1024

#define TAU      4e-3f
#define FIX_CAP  32768
#define FIX_E    8
#define SCL      256.0f
#define SCLQ     16.0f
#define INV_SS   (1.0f / 1048576.0f)  // 2^-20

// BLAS sgemm K-blocking (VERIFIED R9): kc=512 -> blocks {512,512}
#define KBLK 512

typedef unsigned short ushort_t;
typedef __attribute__((ext_vector_type(8))) _Float16 v8h;
typedef __attribute__((ext_vector_type(8))) short  v8s;
typedef __attribute__((ext_vector_type(4))) float  v4f;
typedef __attribute__((ext_vector_type(4))) float  f4;
typedef __attribute__((ext_vector_type(4))) int    i4;
typedef __attribute__((ext_vector_type(4))) short  s4;

#if defined(__has_builtin)
#if __has_builtin(__builtin_amdgcn_global_load_lds)
#define HAS_GLDS 1
#endif
#endif

// ---- helpers -------------------------------------------------------------
__device__ __forceinline__ ushort_t f2bf(float x) {
  unsigned u = __float_as_uint(x);
  u = (u + 0x7FFFu + ((u >> 16) & 1u)) >> 16;  // RNE
  return (ushort_t)u;
}
__device__ __forceinline__ void split2h(float x, ushort_t& h, ushort_t& l) {
  union { _Float16 f; ushort_t u; } a, b;
  a.f = (_Float16)x;
  b.f = (_Float16)(x - (float)a.f);
  h = a.u; l = b.u;
}

__device__ __forceinline__ void gld_lds16(void* lds_dst, const void* g_src) {
#ifdef HAS_GLDS
  __builtin_amdgcn_global_load_lds((const __attribute__((address_space(1))) void*)g_src,
                                   (__attribute__((address_space(3))) void*)lds_dst,
                                   16, 0, 0);
#else
  *(i4*)lds_dst = *(const i4*)g_src;
#endif
}

// XCD-chunked bijective block remap (T1, VERIFIED R11: FETCH 337->167MB).
__device__ __forceinline__ void xcd_remap(int& bx, int& by, int& bz) {
  const int nx = gridDim.x, ny = gridDim.y;
  const int nwg = nx * ny * gridDim.z;
  const int hwid = bx + nx * (by + ny * bz);
  const int work = (hwid & 7) * (nwg >> 3) + (hwid >> 3);
  bx = work % nx;
  const int t = work / nx;
  by = t % ny;
  bz = t / ny;
}

#define WAIT_VM(n) asm volatile("s_waitcnt vmcnt(" #n ")" ::: "memory")

// ---- K0 fused prologue: Q-split | K-split | W-transpose+split | V-transpose
__global__ __launch_bounds__(256)
void k_prep(const float* __restrict__ Q, const float* __restrict__ K,
            const float* __restrict__ W, const float* __restrict__ V,
            ushort_t* __restrict__ Qhi, ushort_t* __restrict__ Qlo,
            ushort_t* __restrict__ Khi, ushort_t* __restrict__ Klo,
            ushort_t* __restrict__ Wthi, ushort_t* __restrict__ Wtlo,
            ushort_t* __restrict__ Vt, int* __restrict__ cnt) {
  const int blk = blockIdx.x;
  const int tid = threadIdx.x;
  if (blk == 0 && tid == 0) *cnt = 0;

  if (blk < 4096) {
    const int sb = blk & 2047;
    const float* x = (blk < 2048) ? Q : K;
    ushort_t* hi = (blk < 2048) ? Qhi : Khi;
    ushort_t* lo = (blk < 2048) ? Qlo : Klo;
    const float scale = (blk < 2048) ? SCLQ : SCL;
    const int n4 = (int)((size_t)B_ * LQ_ * H_ / 4);
    for (int i = sb * 256 + tid; i < n4; i += 2048 * 256) {
      f4 v = ((const f4*)x)[i];
      s4 h, l;
#pragma unroll
      for (int j = 0; j < 4; j++) {
        ushort_t hb, lb; split2h(v[j] * scale, hb, lb);
        h[j] = (short)hb; l[j] = (short)lb;
      }
      ((s4*)hi)[i] = h;
      ((s4*)lo)[i] = l;
    }
    return;
  }

  __shared__ float t[32][33];
  const int tx = tid & 31, ty = tid >> 5;  // (32,8)
  int bx, by, bz, R, C, SPLIT;
  const float* X;
  float scale;
  if (blk < 5120) {  // W: [1024][1024], split
    const int wb = blk - 4096;
    bx = wb & 31; by = wb >> 5; bz = 0; R = H_; C = H_; SPLIT = 1; X = W; scale = SCL;
  } else {           // V: [2048][1024] per batch, no split
    const int vb = blk - 5120;
    bx = vb & 31; by = (vb >> 5) & 63; bz = vb >> 11; R = LK_; C = H_; SPLIT = 0; X = V; scale = 1.0f;
  }
  const float* Xb = X + (size_t)bz * R * C;
  const int c0 = bx * 32, r0 = by * 32;
#pragma unroll
  for (int i = 0; i < 4; i++)
    t[ty + 8 * i][tx] = Xb[(size_t)(r0 + ty + 8 * i) * C + c0 + tx];
  __syncthreads();
#pragma unroll
  for (int i = 0; i < 4; i++) {
    float v = t[tx][ty + 8 * i] * scale;
    size_t o = (size_t)(c0 + ty + 8 * i) * R + r0 + tx;
    if (SPLIT) {
      ushort_t h, l; split2h(v, h, l);
      Wthi[o] = h; Wtlo[o] = l;
    } else {
      (Vt + (size_t)bz * R * C)[o] = f2bf(v);
    }
  }
}

// LDS chunk swizzle (VERIFIED R10, conflicts -> 0): chunk c of row r at slot
// c ^ ((r>>1)&3); pre-swizzled GLOBAL source, linear LDS dest, XOR on read.

// ---- f16x2 GEMM: BM=256, BN=256, BK=32, 8 waves, 2-stage (R14 loop) ------
// Wave-tile 128x64.  MFMA body in PASS-MAJOR order: per A-row, all 4 hh,
// then all 4 hl, then all 4 lh -> dependency distance 4 issues (vs 1),
// covering MFMA latency.  Direct epilogue stores (R16 LDS-staging reverted:
// write traffic proved off-critical-path and the stage added conflicts).
// EPI 0: write f16 hi/lo split.  EPI 1: S, sigmoid G, hat, flag.
template <int EPI>
__global__ __launch_bounds__(512, 1)
void gemm_hx2p(const ushort_t* __restrict__ Ahi, const ushort_t* __restrict__ Alo,
               const ushort_t* __restrict__ Bhi, const ushort_t* __restrict__ Blo,
               int KD, long strideAB, long strideBB, int N,
               ushort_t* __restrict__ OutHi, ushort_t* __restrict__ OutLo, long strideOB,
               float* __restrict__ S, float* __restrict__ G, ushort_t* __restrict__ Hatb,
               const int* __restrict__ mask, int* __restrict__ cnt, int* __restrict__ flist) {
  int bx = blockIdx.x, by = blockIdx.y, bz = blockIdx.z;
  xcd_remap(bx, by, bz);
  const int b  = bz;
  const int m0 = by * 256;
  const int n0 = bx * 256;
  const ushort_t* Ah = Ahi + (size_t)b * strideAB + (size_t)m0 * KD;
  const ushort_t* Al = Alo + (size_t)b * strideAB + (size_t)m0 * KD;
  const ushort_t* Bh = Bhi + (size_t)b * strideBB + (size_t)n0 * KD;
  const ushort_t* Bl = Blo + (size_t)b * strideBB + (size_t)n0 * KD;

  // 2 stages x [A-hi 16K | A-lo 16K | B-hi 16K | B-lo 16K] = 128KB
  __shared__ __attribute__((aligned(16))) char lds[2 * 65536];

  const int tid  = threadIdx.x;        // 0..511
  const int lane = tid & 63;
  const int w    = tid >> 6;           // 0..7
  const int wm   = (w >> 2) * 128;     // wave row base (0/128)
  const int wn   = (w & 3) * 64;       // wave col base (0..192)
  const int fr   = lane & 15;
  const int cq   = lane >> 4;

  v4f acc[8][4] = {};

  const int r4 = tid >> 2;
  const int gc = (tid & 3) ^ ((r4 >> 1) & 3);
  const size_t go1 = (size_t)r4 * KD + gc * 8;
  const size_t go2 = (size_t)(r4 + 128) * KD + gc * 8;
  const int lo16 = tid * 16;

#define STG_HX(t_) do {                                                  \
    char* sb_ = lds + ((t_) & 1) * 65536;                                \
    const int kk_ = (t_) * 32;                                           \
    gld_lds16(sb_ + lo16,          Ah + go1 + kk_);                      \
    gld_lds16(sb_ + 8192  + lo16,  Ah + go2 + kk_);                      \
    gld_lds16(sb_ + 16384 + lo16,  Al + go1 + kk_);                      \
    gld_lds16(sb_ + 24576 + lo16,  Al + go2 + kk_);                      \
    gld_lds16(sb_ + 32768 + lo16,  Bh + go1 + kk_);                      \
    gld_lds16(sb_ + 40960 + lo16,  Bh + go2 + kk_);                      \
    gld_lds16(sb_ + 49152 + lo16,  Bl + go1 + kk_);                      \
    gld_lds16(sb_ + 57344 + lo16,  Bl + go2 + kk_);                      \
  } while (0)

  const int nT = KD / 32;
  STG_HX(0);
  for (int t = 0; t < nT; ++t) {
    WAIT_VM(0);                     // own stage(t) complete
    __builtin_amdgcn_s_barrier();   // stage(t) published; buf (t+1)&1 free
    if (t + 1 < nT) STG_HX(t + 1);  // overlaps MFMA below

    const char* sb = lds + (t & 1) * 65536;
    v8h b_h[4], b_l[4];
#pragma unroll
    for (int j = 0; j < 4; j++) {
      const int Rb = wn + j * 16 + fr;
      const int ob = Rb * 64 + ((cq ^ ((Rb >> 1) & 3)) << 4);
      b_h[j] = *(const v8h*)(sb + 32768 + ob);
      b_l[j] = *(const v8h*)(sb + 49152 + ob);
    }
    __builtin_amdgcn_s_setprio(1);
#pragma unroll
    for (int i = 0; i < 8; i++) {
      const int Ra = wm + i * 16 + fr;
      const int oa = Ra * 64 + ((cq ^ ((Ra >> 1) & 3)) << 4);
      v8h a_h = *(const v8h*)(sb + oa);
      v8h a_l = *(const v8h*)(sb + 16384 + oa);
      // pass-major: 4 independent MFMAs per pass; same-acc reuse distance = 4
#pragma unroll
      for (int j = 0; j < 4; j++)
        acc[i][j] = __builtin_amdgcn_mfma_f32_16x16x32_f16(a_h, b_h[j], acc[i][j], 0, 0, 0);
#pragma unroll
      for (int j = 0; j < 4; j++)
        acc[i][j] = __builtin_amdgcn_mfma_f32_16x16x32_f16(a_h, b_l[j], acc[i][j], 0, 0, 0);
#pragma unroll
      for (int j = 0; j < 4; j++)
        acc[i][j] = __builtin_amdgcn_mfma_f32_16x16x32_f16(a_l, b_h[j], acc[i][j], 0, 0, 0);
    }
    __builtin_amdgcn_s_setprio(0);
  }
#undef STG_HX

  // epilogue: C/D layout col = lane&15, row = (lane>>4)*4 + reg (direct stores)
  const int rg = (lane >> 4) * 4;
#pragma unroll
  for (int i = 0; i < 8; i++)
#pragma unroll
    for (int j = 0; j < 4; j++)
#pragma unroll
      for (int r = 0; r < 4; r++) {
        const int grow = m0 + wm + i * 16 + rg + r;
        const int gcol = n0 + wn + j * 16 + fr;
        const float v = acc[i][j][r];
        if (EPI == 0) {
          size_t o = (size_t)b * strideOB + (size_t)grow * N + gcol;
          ushort_t h, l; split2h(v, h, l);
          OutHi[o] = h; OutLo[o] = l;
        } else {
          size_t o = ((size_t)b * LQ_ + grow) * N + gcol;
          const float sv = v * INV_SS;
          S[o] = sv;
          int mk = mask[b * N + gcol];
          const float g = mk ? 1.0f / (1.0f + expf(-sv)) : 0.0f;
          G[o] = g;
          Hatb[o] = (g > 0.5f) ? (ushort_t)0x3F80 : (ushort_t)0;
          if (mk && fabsf(sv) < TAU) {
            int idx = atomicAdd(cnt, 1);
            if (idx < FIX_CAP) flist[idx] = (b << 22) | (grow << 11) | gcol;
          }
        }
      }
}

// ---- BLAS-sgemm emulation fixup (kc=512, VERIFIED) -----------------------
__global__ __launch_bounds__(256)
void k_fix_blas(const int* __restrict__ cnt, const int* __restrict__ flist,
                const float* __restrict__ Q, const float* __restrict__ Kx,
                const float* __restrict__ W, float* __restrict__ S,
                float* __restrict__ G, ushort_t* __restrict__ Hatb) {
  const int n = min(*cnt, FIX_CAP);
  const int base = blockIdx.x * FIX_E;
  if (base >= n) return;
  const int ne = min(FIX_E, n - base);
  const int tid = threadIdx.x;

  __shared__ float qs[FIX_E][H_];
  __shared__ float aA[FIX_E][H_];
  __shared__ int   ent[FIX_E];

  if (tid < FIX_E) ent[tid] = flist[base + ((tid < ne) ? tid : 0)];
  __syncthreads();

  for (int e = 0; e < FIX_E; e++) {
    const int en = ent[e];
    const int b = en >> 22, q = (en >> 11) & 2047;
    const float* Qr = Q + ((size_t)b * LQ_ + q) * H_;
    for (int i = tid; i < H_; i += 256) qs[e][i] = Qr[i];
  }
  __syncthreads();

  float atot[FIX_E][4];
  float acc[FIX_E][4];
  const float* Wp = W + tid * 4;
#pragma unroll
  for (int blk = 0; blk < 2; blk++) {
    const int h0 = blk * KBLK;
    const int h1 = h0 + KBLK;
#pragma unroll
    for (int e = 0; e < FIX_E; e++)
#pragma unroll
      for (int j = 0; j < 4; j++) acc[e][j] = 0.f;
    for (int h = h0; h < h1; h++) {
      f4 w = *(const f4*)(Wp + (size_t)h * H_);
#pragma unroll
      for (int e = 0; e < FIX_E; e++) {
        const float qv = qs[e][h];
        acc[e][0] = fmaf(qv, w[0], acc[e][0]);
        acc[e][1] = fmaf(qv, w[1], acc[e][1]);
        acc[e][2] = fmaf(qv, w[2], acc[e][2]);
        acc[e][3] = fmaf(qv, w[3], acc[e][3]);
      }
    }
#pragma unroll
    for (int e = 0; e < FIX_E; e++)
#pragma unroll
      for (int j = 0; j < 4; j++)
        atot[e][j] = (blk == 0) ? acc[e][j] : __fadd_rn(atot[e][j], acc[e][j]);
  }
#pragma unroll
  for (int e = 0; e < FIX_E; e++) {
    aA[e][tid * 4 + 0] = atot[e][0];
    aA[e][tid * 4 + 1] = atot[e][1];
    aA[e][tid * 4 + 2] = atot[e][2];
    aA[e][tid * 4 + 3] = atot[e][3];
  }
  __syncthreads();

  if (tid < ne) {
    const int e = tid;
    const int en = ent[e];
    const int b = en >> 22, q = (en >> 11) & 2047, k = en & 2047;
    const float* Kr = Kx + ((size_t)b * LK_ + k) * H_;
    const float* Ar = aA[e];
    float stot = 0.f;
#pragma unroll
    for (int blk = 0; blk < 2; blk++) {
      const int d0 = blk * KBLK;
      const int d1 = d0 + KBLK;
      float a = 0.f;
#pragma unroll 16
      for (int d = d0; d < d1; d++) a = fmaf(Ar[d], Kr[d], a);
      stot = (blk == 0) ? a : __fadd_rn(stot, a);
    }
    size_t o = ((size_t)b * LQ_ + q) * LK_ + k;
    S[o] = stot;
    const float g = 1.0f / (1.0f + expf(-stot));
    G[o] = g;
    Hatb[o] = (g > 0.5f) ? (ushort_t)0x3F80 : (ushort_t)0;
  }
}

// ---- K3: in-place masked row softmax; emits bf16 P -----------------------
__global__ void k_softmax(float* __restrict__ S, const int* __restrict__ mask,
                          ushort_t* __restrict__ Pb) {
  const int row = blockIdx.x;
  const int b   = row >> 11;
  float* Sr = S + (size_t)row * LK_;
  const int* mr = mask + b * LK_;
  const int tid = threadIdx.x;
  const int c0 = tid * 8;

  float v[8]; int mk[8];
  f4 v0 = *(const f4*)&Sr[c0];
  f4 v1 = *(const f4*)&Sr[c0 + 4];
  i4 m0 = *(const i4*)&mr[c0];
  i4 m1 = *(const i4*)&mr[c0 + 4];
#pragma unroll
  for (int j = 0; j < 4; j++) { v[j] = v0[j]; v[4 + j] = v1[j]; mk[j] = m0[j]; mk[4 + j] = m1[j]; }

  float mx = -INFINITY;
#pragma unroll
  for (int j = 0; j < 8; j++) if (mk[j]) mx = fmaxf(mx, v[j]);
#pragma unroll
  for (int off = 32; off; off >>= 1) mx = fmaxf(mx, __shfl_xor(mx, off));
  __shared__ float redm[4], reds[4];
  const int lane = tid & 63, wid = tid >> 6;
  if (lane == 0) redm[wid] = mx;
  __syncthreads();
  mx = fmaxf(fmaxf(redm[0], redm[1]), fmaxf(redm[2], redm[3]));

  float e[8], sum = 0.f;
#pragma unroll
  for (int j = 0; j < 8; j++) { e[j] = mk[j] ? expf(v[j] - mx) : 0.f; sum += e[j]; }
#pragma unroll
  for (int off = 32; off; off >>= 1) sum += __shfl_xor(sum, off);
  if (lane == 0) reds[wid] = sum;
  __syncthreads();
  sum = reds[0] + reds[1] + reds[2] + reds[3];
  const float inv = 1.0f / sum;

  f4 o0, o1;
  v8s pb;
#pragma unroll
  for (int j = 0; j < 4; j++) {
    o0[j] = e[j] * inv; o1[j] = e[4 + j] * inv;
    pb[j] = (short)f2bf(o0[j]); pb[4 + j] = (short)f2bf(o1[j]);
  }
  *(f4*)&Sr[c0] = o0;
  *(f4*)&Sr[c0 + 4] = o1;
  *(v8s*)&Pb[(size_t)row * LK_ + c0] = pb;
}

// ---- pipelined fused dual PV: BM=128, BN=256, BK=32, 8 waves, 3-stage ----
//   O0 = Pb . Vt^T,  O1 = hatb . Vt^T  (B staged once, shared)
__global__ __launch_bounds__(512, 1)
void gemm_pv2p(const ushort_t* __restrict__ P, const ushort_t* __restrict__ Hb,
               const ushort_t* __restrict__ Bt,
               float* __restrict__ O0, float* __restrict__ O1) {
  int bx = blockIdx.x, by = blockIdx.y, bz = blockIdx.z;
  xcd_remap(bx, by, bz);
  const int b  = bz;
  const int m0 = by * 128;
  const int n0 = bx * 256;
  const ushort_t* Pa = P  + ((size_t)b * LQ_ + m0) * (size_t)LK_;
  const ushort_t* Ha = Hb + ((size_t)b * LQ_ + m0) * (size_t)LK_;
  const ushort_t* Bb = Bt + ((size_t)b * H_  + n0) * (size_t)LK_;

  __shared__ __attribute__((aligned(16))) char lds[3 * 32768];

  const int tid  = threadIdx.x;
  const int lane = tid & 63;
  const int w    = tid >> 6;
  const int wm   = (w >> 2) * 64;
  const int wn   = (w & 3) * 64;
  const int fr   = lane & 15;
  const int cq   = lane >> 4;

  v4f acc0[4][4] = {}, acc1[4][4] = {};

  const int r4 = tid >> 2;
  const int gc = (tid & 3) ^ ((r4 >> 1) & 3);
  const size_t goA  = (size_t)r4 * LK_ + gc * 8;
  const size_t goB1 = (size_t)(r4 + 128) * LK_ + gc * 8;
  const int lo16 = tid * 16;

#define STG_PV(t_) do {                                                  \
    char* sb = lds + ((t_) % 3) * 32768;                                 \
    const int kk = (t_) * 32;                                            \
    gld_lds16(sb + lo16,          Pa + goA  + kk);                       \
    gld_lds16(sb + 8192 + lo16,   Ha + goA  + kk);                       \
    gld_lds16(sb + 16384 + lo16,  Bb + goA  + kk);                       \
    gld_lds16(sb + 24576 + lo16,  Bb + goB1 + kk);                       \
  } while (0)

  const int nT = LK_ / 32;   // 64
  STG_PV(0);
  STG_PV(1);
  for (int t = 0; t < nT; ++t) {
    if (t + 1 < nT) WAIT_VM(4);
    else            WAIT_VM(0);
    __builtin_amdgcn_s_barrier();

    const char* sb = lds + (t % 3) * 32768;
    v8s pf[4], hf[4], bf[4];
#pragma unroll
    for (int i = 0; i < 4; i++) {
      const int Ra = wm + i * 16 + fr;
      const int oa = Ra * 64 + ((cq ^ ((Ra >> 1) & 3)) << 4);
      pf[i] = *(const v8s*)(sb + oa);
      hf[i] = *(const v8s*)(sb + 8192 + oa);
      const int Rb = wn + i * 16 + fr;
      bf[i] = *(const v8s*)(sb + 16384 + Rb * 64 + ((cq ^ ((Rb >> 1) & 3)) << 4));
    }
    if (t + 2 < nT) STG_PV(t + 2);

    __builtin_amdgcn_s_setprio(1);
#pragma unroll
    for (int i = 0; i < 4; i++)
#pragma unroll
      for (int j = 0; j < 4; j++) {
        acc0[i][j] = __builtin_amdgcn_mfma_f32_16x16x32_bf16(pf[i], bf[j], acc0[i][j], 0, 0, 0);
        acc1[i][j] = __builtin_amdgcn_mfma_f32_16x16x32_bf16(hf[i], bf[j], acc1[i][j], 0, 0, 0);
      }
    __builtin_amdgcn_s_setprio(0);
  }
#undef STG_PV

  const int rg = (lane >> 4) * 4;
#pragma unroll
  for (int i = 0; i < 4; i++)
#pragma unroll
    for (int j = 0; j < 4; j++)
#pragma unroll
      for (int r = 0; r < 4; r++) {
        const int grow = m0 + wm + i * 16 + rg + r;
        const int gcol = n0 + wn + j * 16 + fr;
        const size_t o = ((size_t)b * LQ_ + grow) * H_ + gcol;
        O0[o] = acc0[i][j][r];
        O1[o] = acc1[i][j][r];
      }
}

// ---- launch --------------------------------------------------------------
extern "C" void kernel_launch(void* const* d_in, const int* in_sizes, int n_in,
                              void* d_out, int out_size, void* d_ws, size_t ws_size,
                              hipStream_t stream) {
  const float* Q = (const float*)d_in[0];
  const float* K = (const float*)d_in[1];
  const float* V = (const float*)d_in[2];
  const float* W = (const float*)d_in[3];
  const int* mask = (const int*)d_in[4];

  float* out0 = (float*)d_out;
  float* out1 = out0 + (size_t)B_ * LQ_ * H_;
  float* out2 = out1 + (size_t)B_ * LQ_ * H_;
  float* out3 = out2 + (size_t)B_ * LQ_ * LK_;

  const size_t NQ = (size_t)B_ * LQ_ * H_;
  char* ws = (char*)d_ws;
  int* cnt   = (int*)ws;                    ws += 256;
  int* flist = (int*)ws;                    ws += FIX_CAP * 4;
  ushort_t* Qhi = (ushort_t*)ws;            ws += NQ * 2;
  ushort_t* Qlo = (ushort_t*)ws;            ws += NQ * 2;
  ushort_t* Khi = (ushort_t*)ws;            ws += NQ * 2;
  ushort_t* Klo = (ushort_t*)ws;            ws += NQ * 2;
  ushort_t* Ahi = (ushort_t*)ws;            ws += NQ * 2;
  ushort_t* Alo = (ushort_t*)ws;            ws += NQ * 2;
  ushort_t* Vt  = (ushort_t*)ws;            ws += NQ * 2;
  ushort_t* Wthi = (ushort_t*)ws;           ws += (size_t)H_ * H_ * 2;
  ushort_t* Wtlo = (ushort_t*)ws;

  ushort_t* hatb = Qhi;   // dead after K1
  ushort_t* Pb   = Ahi;   // dead after K2

  // K0: fused prologue (splits + transposes + cnt zero)
  k_prep<<<21504, 256, 0, stream>>>(Q, K, W, V, Qhi, Qlo, Khi, Klo,
                                    Wthi, Wtlo, Vt, cnt);

  // K1: A' = (16Q) @ (256 W)  (f16x2 3-pass)
  gemm_hx2p<0><<<dim3(H_ / 256, LQ_ / 256, B_), 512, 0, stream>>>(
      Qhi, Qlo, Wthi, Wtlo, H_, (long)LQ_ * H_, 0L, H_,
      Ahi, Alo, (long)LQ_ * H_, nullptr, nullptr, nullptr, nullptr, nullptr, nullptr);

  // K2: s' = A' @ (256 K)^T  -> S, G, hat, flags
  gemm_hx2p<1><<<dim3(LK_ / 256, LQ_ / 256, B_), 512, 0, stream>>>(
      Ahi, Alo, Khi, Klo, H_, (long)LQ_ * H_, (long)LK_ * H_, LK_,
      nullptr, nullptr, 0L, out2, out3, hatb, mask, cnt, flist);

  // K2.5: BLAS {512,512}-blocked f32 emulation fixup
  k_fix_blas<<<FIX_CAP / FIX_E, 256, 0, stream>>>(cnt, flist, Q, K, W, out2, out3, hatb);

  // K3: masked softmax; emits bf16 P
  k_softmax<<<B_ * LQ_, 256, 0, stream>>>(out2, mask, Pb);

  // K4+K5 fused: dual PV -> out0, out1
  gemm_pv2p<<<dim3(H_ / 256, LQ_ / 128, B_), 512, 0, stream>>>(Pb, hatb, Vt, out0, out1);
}